// Round 1
// baseline (321.722 us; speedup 1.0000x reference)
//
#include <hip/hip_runtime.h>
#include <math.h>

#define DD 768
#define DD4 192          // DD/4
#define KK 16
#define EPSV 1e-5f

// One wave (64 lanes) handles one row of 768 floats (12 floats = 3 float4 per lane).
// Centroids (16x768 fp32 = 48 KB) staged in LDS once per block, reused across rows.
// LDS: 48 KB centroids + small -> 3 blocks/CU.
__global__ __launch_bounds__(256)
void sln_kernel(const float* __restrict__ x,
                const float* __restrict__ weights,
                const float* __restrict__ biases,
                const float* __restrict__ centroids,
                float* __restrict__ out,       // [nrows*DD]
                float* __restrict__ bkt,       // [nrows] bucket idx as float
                int nrows)
{
    __shared__ float cs[KK * DD];
    __shared__ float c2s[KK];
    __shared__ float c2part[256];

    const int tid  = threadIdx.x;
    const int lane = tid & 63;
    const int wave = tid >> 6;

    // stage centroids to LDS (coalesced float4)
    {
        const float4* c4 = (const float4*)centroids;
        float4* cs4w = (float4*)cs;
        for (int i = tid; i < KK * DD4; i += 256) cs4w[i] = c4[i];
    }
    __syncthreads();

    // c2[k] = sum_d centroids[k][d]^2 (block-wide partial + small serial combine)
    {
        int k = tid >> 4, t = tid & 15;
        float p = 0.f;
        #pragma unroll
        for (int j = 0; j < DD / 16; ++j) {
            float v = cs[k * DD + t + 16 * j];
            p += v * v;
        }
        c2part[tid] = p;
    }
    __syncthreads();
    if (tid < KK) {
        float sacc = 0.f;
        #pragma unroll
        for (int i = 0; i < 16; ++i) sacc += c2part[tid * 16 + i];
        c2s[tid] = sacc;
    }
    __syncthreads();

    const float4* cs4 = (const float4*)cs;

    for (int row = blockIdx.x * 4 + wave; row < nrows; row += gridDim.x * 4) {
        const float4* xr = (const float4*)(x + (size_t)row * DD);
        float4 v0 = xr[lane];
        float4 v1 = xr[lane + 64];
        float4 v2 = xr[lane + 128];

        float s  = v0.x + v0.y + v0.z + v0.w
                 + v1.x + v1.y + v1.z + v1.w
                 + v2.x + v2.y + v2.z + v2.w;
        float ss = v0.x*v0.x + v0.y*v0.y + v0.z*v0.z + v0.w*v0.w
                 + v1.x*v1.x + v1.y*v1.y + v1.z*v1.z + v1.w*v1.w
                 + v2.x*v2.x + v2.y*v2.y + v2.z*v2.z + v2.w*v2.w;

        #pragma unroll
        for (int m = 1; m < 64; m <<= 1) {
            s  += __shfl_xor(s,  m, 64);
            ss += __shfl_xor(ss, m, 64);
        }

        const float mean = s * (1.f / DD);
        const float var  = ss * (1.f / DD) - mean * mean;
        const float rstd = 1.f / sqrtf(var + EPSV);
        const float x2   = ss;   // sum of squares (matches reference x2)

        // nearest centroid: sq = x2 - 2*dot + c2, first-min (strict <, k ascending)
        float best = INFINITY;
        int   bk   = 0;
        #pragma unroll
        for (int k = 0; k < KK; ++k) {
            float4 c0 = cs4[k * DD4 + lane];
            float4 c1 = cs4[k * DD4 + lane + 64];
            float4 c2 = cs4[k * DD4 + lane + 128];
            float d = v0.x*c0.x + v0.y*c0.y + v0.z*c0.z + v0.w*c0.w
                    + v1.x*c1.x + v1.y*c1.y + v1.z*c1.z + v1.w*c1.w
                    + v2.x*c2.x + v2.y*c2.y + v2.z*c2.z + v2.w*c2.w;
            #pragma unroll
            for (int m = 1; m < 64; m <<= 1) d += __shfl_xor(d, m, 64);
            float sq = (x2 - 2.f * d) + c2s[k];
            if (sq < best) { best = sq; bk = k; }
        }
        if (lane == 0) bkt[row] = (float)bk;

        const float4* w4 = (const float4*)(weights + (size_t)bk * DD);
        const float4* b4 = (const float4*)(biases  + (size_t)bk * DD);
        float4* o4 = (float4*)(out + (size_t)row * DD);

        #pragma unroll
        for (int j = 0; j < 3; ++j) {
            float4 xv = (j == 0) ? v0 : (j == 1) ? v1 : v2;
            float4 wv = w4[lane + 64 * j];
            float4 bv = b4[lane + 64 * j];
            float4 o;
            o.x = (xv.x - mean) * rstd * wv.x + bv.x;
            o.y = (xv.y - mean) * rstd * wv.y + bv.y;
            o.z = (xv.z - mean) * rstd * wv.z + bv.z;
            o.w = (xv.w - mean) * rstd * wv.w + bv.w;
            o4[lane + 64 * j] = o;
        }
    }
}

extern "C" void kernel_launch(void* const* d_in, const int* in_sizes, int n_in,
                              void* d_out, int out_size, void* d_ws, size_t ws_size,
                              hipStream_t stream) {
    const float* x         = (const float*)d_in[0];
    const float* weights   = (const float*)d_in[1];
    const float* biases    = (const float*)d_in[2];
    const float* centroids = (const float*)d_in[3];

    const int nrows = in_sizes[0] / DD;   // B*S = 32768

    float* out = (float*)d_out;
    float* bkt = out + (size_t)nrows * DD;

    dim3 grid(2048), block(256);
    hipLaunchKernelGGL(sln_kernel, grid, block, 0, stream,
                       x, weights, biases, centroids, out, bkt, nrows);
}

// Round 2
// 198.243 us; speedup vs baseline: 1.6229x; 1.6229x over previous
//
#include <hip/hip_runtime.h>
#include <math.h>

#define DD 768
#define DD4 192          // DD/4
#define KK 16
#define EPSV 1e-5f
#define SCRS 38          // 36 value slots + 2 pad per quad

// One wave handles TWO rows per iteration. Per-lane partials (s, ss, 16 dots)
// -> 2-step quad shuffle reduce -> LDS transpose (16 quads x 36 values)
// -> 36 lanes sum 16 values each with full ILP. No long butterfly chains.
// LDS: 48 KB centroids + 9.5 KB scratch -> 2 blocks/CU, 8 waves/CU.
__global__ __launch_bounds__(256, 2)
void sln_kernel(const float* __restrict__ x,
                const float* __restrict__ weights,
                const float* __restrict__ biases,
                const float* __restrict__ centroids,
                float* __restrict__ out,       // [nrows*DD]
                float* __restrict__ bkt,       // [nrows] bucket idx as float
                int nrows)
{
    __shared__ float cs[KK * DD];          // 48 KB
    __shared__ float c2s[KK];
    __shared__ float scr[4][16][SCRS];     // per-wave transpose scratch

    const int tid  = threadIdx.x;
    const int lane = tid & 63;
    const int wave = tid >> 6;

    // stage centroids to LDS (coalesced float4)
    {
        const float4* c4 = (const float4*)centroids;
        float4* cs4w = (float4*)cs;
        for (int i = tid; i < KK * DD4; i += 256) cs4w[i] = c4[i];
    }
    __syncthreads();

    // c2[k] = sum_d centroids[k][d]^2  (reuse scr as 256-float scratch)
    {
        float* part = &scr[0][0][0];
        int k = tid >> 4, t = tid & 15;
        float p = 0.f;
        #pragma unroll
        for (int j = 0; j < DD / 16; ++j) {
            float v = cs[k * DD + t + 16 * j];
            p += v * v;
        }
        part[tid] = p;
    }
    __syncthreads();
    if (tid < KK) {
        float* part = &scr[0][0][0];
        float sacc = 0.f;
        #pragma unroll
        for (int i = 0; i < 16; ++i) sacc += part[tid * 16 + i];
        c2s[tid] = sacc;
    }
    __syncthreads();

    const float4* cs4 = (const float4*)cs;
    const int gw = blockIdx.x * 4 + wave;
    const int wstride = gridDim.x * 4;

    for (int pair = gw; pair * 2 < nrows; pair += wstride) {
        const int r0 = pair * 2;
        const int r1 = r0 + 1;

        const float4* xr0 = (const float4*)(x + (size_t)r0 * DD);
        const float4* xr1 = (const float4*)(x + (size_t)r1 * DD);
        float4 a0 = xr0[lane], a1 = xr0[lane + 64], a2 = xr0[lane + 128];
        float4 b0 = xr1[lane], b1 = xr1[lane + 64], b2 = xr1[lane + 128];

        // per-lane partials
        float s0 = a0.x+a0.y+a0.z+a0.w + a1.x+a1.y+a1.z+a1.w + a2.x+a2.y+a2.z+a2.w;
        float ss0 = a0.x*a0.x+a0.y*a0.y+a0.z*a0.z+a0.w*a0.w
                  + a1.x*a1.x+a1.y*a1.y+a1.z*a1.z+a1.w*a1.w
                  + a2.x*a2.x+a2.y*a2.y+a2.z*a2.z+a2.w*a2.w;
        float s1 = b0.x+b0.y+b0.z+b0.w + b1.x+b1.y+b1.z+b1.w + b2.x+b2.y+b2.z+b2.w;
        float ss1 = b0.x*b0.x+b0.y*b0.y+b0.z*b0.z+b0.w*b0.w
                  + b1.x*b1.x+b1.y*b1.y+b1.z*b1.z+b1.w*b1.w
                  + b2.x*b2.x+b2.y*b2.y+b2.z*b2.z+b2.w*b2.w;

        float d0[KK], d1[KK];
        #pragma unroll
        for (int k = 0; k < KK; ++k) {
            float4 c0 = cs4[k * DD4 + lane];
            float4 c1 = cs4[k * DD4 + lane + 64];
            float4 c2 = cs4[k * DD4 + lane + 128];
            d0[k] = a0.x*c0.x + a0.y*c0.y + a0.z*c0.z + a0.w*c0.w
                  + a1.x*c1.x + a1.y*c1.y + a1.z*c1.z + a1.w*c1.w
                  + a2.x*c2.x + a2.y*c2.y + a2.z*c2.z + a2.w*c2.w;
            d1[k] = b0.x*c0.x + b0.y*c0.y + b0.z*c0.z + b0.w*c0.w
                  + b1.x*c1.x + b1.y*c1.y + b1.z*c1.z + b1.w*c1.w
                  + b2.x*c2.x + b2.y*c2.y + b2.z*c2.z + b2.w*c2.w;
        }

        // 2-step quad reduce (independent shuffles, short chains)
        #pragma unroll
        for (int k = 0; k < KK; ++k) {
            d0[k] += __shfl_xor(d0[k], 1); d0[k] += __shfl_xor(d0[k], 2);
            d1[k] += __shfl_xor(d1[k], 1); d1[k] += __shfl_xor(d1[k], 2);
        }
        s0 += __shfl_xor(s0, 1);  s0 += __shfl_xor(s0, 2);
        ss0 += __shfl_xor(ss0, 1); ss0 += __shfl_xor(ss0, 2);
        s1 += __shfl_xor(s1, 1);  s1 += __shfl_xor(s1, 2);
        ss1 += __shfl_xor(ss1, 1); ss1 += __shfl_xor(ss1, 2);

        // quad leaders write 36 values (row0: 0..17, row1: 18..35)
        if ((lane & 3) == 0) {
            int q = lane >> 2;
            float* p = &scr[wave][q][0];
            #pragma unroll
            for (int k = 0; k < KK; ++k) { p[k] = d0[k]; p[18 + k] = d1[k]; }
            p[16] = s0; p[17] = ss0; p[34] = s1; p[35] = ss1;
        }
        __asm__ volatile("" ::: "memory");   // intra-wave LDS RAW: in-order per wave

        // transpose read: lanes 0..17 -> row0 values, lanes 32..49 -> row1 values
        int slot = (lane < 32) ? lane : (18 + (lane - 32));
        float T = 0.f;
        if (lane < 18 || (lane >= 32 && lane < 50)) {
            float t0 = 0.f, t1 = 0.f, t2 = 0.f, t3 = 0.f;
            #pragma unroll
            for (int q = 0; q < 16; q += 4) {
                t0 += scr[wave][q + 0][slot];
                t1 += scr[wave][q + 1][slot];
                t2 += scr[wave][q + 2][slot];
                t3 += scr[wave][q + 3][slot];
            }
            T = (t0 + t1) + (t2 + t3);
        }
        __asm__ volatile("" ::: "memory");

        // broadcast row sums
        float sA  = __shfl(T, 16), ssA = __shfl(T, 17);
        float sB  = __shfl(T, 48), ssB = __shfl(T, 49);

        // argmin over 16 dists (lanes 0..15 = row0, 32..47 = row1)
        int v = lane & 15;
        float ssSel = (lane & 32) ? ssB : ssA;
        float sq = (ssSel - 2.f * T) + c2s[v];
        int idx = v;
        #pragma unroll
        for (int m = 1; m < 16; m <<= 1) {
            float osq = __shfl_xor(sq, m);
            int   oidx = __shfl_xor(idx, m);
            bool take = (osq < sq) || (osq == sq && oidx < idx);
            sq  = take ? osq  : sq;
            idx = take ? oidx : idx;
        }
        int bk0 = __builtin_amdgcn_readlane(idx, 0);
        int bk1 = __builtin_amdgcn_readlane(idx, 32);

        float mean0 = sA * (1.f / DD);
        float mean1 = sB * (1.f / DD);
        float rstd0 = 1.f / sqrtf(ssA * (1.f / DD) - mean0 * mean0 + EPSV);
        float rstd1 = 1.f / sqrtf(ssB * (1.f / DD) - mean1 * mean1 + EPSV);

        if (lane == 0) {
            bkt[r0] = (float)bk0;
            bkt[r1] = (float)bk1;
        }

        const float4* w0 = (const float4*)(weights + (size_t)bk0 * DD);
        const float4* g0 = (const float4*)(biases  + (size_t)bk0 * DD);
        const float4* w1 = (const float4*)(weights + (size_t)bk1 * DD);
        const float4* g1 = (const float4*)(biases  + (size_t)bk1 * DD);
        float4* o0 = (float4*)(out + (size_t)r0 * DD);
        float4* o1 = (float4*)(out + (size_t)r1 * DD);

        #pragma unroll
        for (int j = 0; j < 3; ++j) {
            float4 xv = (j == 0) ? a0 : (j == 1) ? a1 : a2;
            float4 wv = w0[lane + 64 * j];
            float4 bv = g0[lane + 64 * j];
            float4 o;
            o.x = (xv.x - mean0) * rstd0 * wv.x + bv.x;
            o.y = (xv.y - mean0) * rstd0 * wv.y + bv.y;
            o.z = (xv.z - mean0) * rstd0 * wv.z + bv.z;
            o.w = (xv.w - mean0) * rstd0 * wv.w + bv.w;
            o0[lane + 64 * j] = o;
        }
        #pragma unroll
        for (int j = 0; j < 3; ++j) {
            float4 xv = (j == 0) ? b0 : (j == 1) ? b1 : b2;
            float4 wv = w1[lane + 64 * j];
            float4 bv = g1[lane + 64 * j];
            float4 o;
            o.x = (xv.x - mean1) * rstd1 * wv.x + bv.x;
            o.y = (xv.y - mean1) * rstd1 * wv.y + bv.y;
            o.z = (xv.z - mean1) * rstd1 * wv.z + bv.z;
            o.w = (xv.w - mean1) * rstd1 * wv.w + bv.w;
            o1[lane + 64 * j] = o;
        }
    }
}

extern "C" void kernel_launch(void* const* d_in, const int* in_sizes, int n_in,
                              void* d_out, int out_size, void* d_ws, size_t ws_size,
                              hipStream_t stream) {
    const float* x         = (const float*)d_in[0];
    const float* weights   = (const float*)d_in[1];
    const float* biases    = (const float*)d_in[2];
    const float* centroids = (const float*)d_in[3];

    const int nrows = in_sizes[0] / DD;   // B*S = 32768

    float* out = (float*)d_out;
    float* bkt = out + (size_t)nrows * DD;

    dim3 grid(2048), block(256);
    hipLaunchKernelGGL(sln_kernel, grid, block, 0, stream,
                       x, weights, biases, centroids, out, bkt, nrows);
}